// Round 13
// baseline (447.486 us; speedup 1.0000x reference)
//
#include <hip/hip_runtime.h>
#include <stdint.h>

#define INCH 512
#define HIDW 512
#define CATW 2560
#define OUTW 256
#define BN_EPS 1e-5f
#define TS 1024   // scan tile

typedef __bf16 bf16x8 __attribute__((ext_vector_type(8)));
typedef float f32x4 __attribute__((ext_vector_type(4)));

__device__ __forceinline__ unsigned short f2bf(float f) {
  union { float f; unsigned u; } v; v.f = f;
  unsigned r = v.u + 0x7FFFu + ((v.u >> 16) & 1u);   // RNE
  return (unsigned short)(r >> 16);
}

__device__ __forceinline__ float bf2f(unsigned short u) {
  union { unsigned u; float f; } v; v.u = ((unsigned)u) << 16; return v.f;
}

__device__ __forceinline__ void pack4(unsigned short* dst, float a, float b, float c, float d) {
  unsigned lo = (unsigned)f2bf(a) | ((unsigned)f2bf(b) << 16);
  unsigned hi = (unsigned)f2bf(c) | ((unsigned)f2bf(d) << 16);
  *reinterpret_cast<uint2*>(dst) = make_uint2(lo, hi);
}

// ---------------- conversion / packing kernels ----------------

__global__ void cvt_bf16_kernel(const float* __restrict__ in, unsigned short* __restrict__ out, int n4) {
  int g = blockIdx.x * blockDim.x + threadIdx.x;
  if (g >= n4) return;
  int base = g * 4;
  float4 v = *reinterpret_cast<const float4*>(in + base);
  pack4(out + base, v.x, v.y, v.z, v.w);
}

// w1[z*512+j][kk] = kk<512 ? Wl5[z][j][kk] : Wr5[z][j][kk-512]   (2560 x 1024 row-major)
__global__ void pack_w1_kernel(const float* __restrict__ Wl, const float* __restrict__ Wr,
                               unsigned short* __restrict__ out) {
  int g = blockIdx.x * blockDim.x + threadIdx.x;
  int base = g * 4;
  if (base >= 5 * 512 * 1024) return;
  int zj = base >> 10;
  int kk = base & 1023;
  const float* src = (kk < 512) ? (Wl + (size_t)zj * 512 + kk)
                                : (Wr + (size_t)zj * 512 + (kk - 512));
  float4 v = *reinterpret_cast<const float4*>(src);
  pack4(out + base, v.x, v.y, v.z, v.w);
}

// W[j2][c] = j2<256 ? Wa[j2][c] : Wb[j2-256][c]   (512 x 2560 row-major)
__global__ void pack_lr_kernel(const float* __restrict__ Wa, const float* __restrict__ Wb,
                               unsigned short* __restrict__ out) {
  int g = blockIdx.x * blockDim.x + threadIdx.x;
  int base = g * 4;
  if (base >= 512 * CATW) return;
  int j2 = base / CATW;
  int c = base % CATW;
  const float* src = (j2 < OUTW) ? (Wa + (size_t)j2 * CATW + c)
                                 : (Wb + (size_t)(j2 - OUTW) * CATW + c);
  float4 v = *reinterpret_cast<const float4*>(src);
  pack4(out + base, v.x, v.y, v.z, v.w);
}

// ---------------- CSR build: key = dst*5 + rel ----------------

__global__ void hist_kernel(const int* __restrict__ ei, const int* __restrict__ ea,
                            int* __restrict__ cnt, int E) {
  int e = blockIdx.x * 256 + threadIdx.x;
  if (e >= E) return;
  atomicAdd(&cnt[ei[E + e] * 5 + ea[e]], 1);
}

__global__ void scan1_kernel(const int* __restrict__ in, int* __restrict__ out,
                             int* __restrict__ bsum, int n) {
  __shared__ int lds[256];
  int t = threadIdx.x;
  int base = blockIdx.x * TS + t * 4;
  int4 v = make_int4(0, 0, 0, 0);
  if (base + 3 < n) v = *reinterpret_cast<const int4*>(in + base);
  else {
    if (base < n) v.x = in[base];
    if (base + 1 < n) v.y = in[base + 1];
    if (base + 2 < n) v.z = in[base + 2];
    if (base + 3 < n) v.w = in[base + 3];
  }
  int s = v.x + v.y + v.z + v.w;
  lds[t] = s;
  __syncthreads();
  for (int o = 1; o < 256; o <<= 1) {
    int a = (t >= o) ? lds[t - o] : 0;
    __syncthreads();
    lds[t] += a;
    __syncthreads();
  }
  int excl = lds[t] - s;
  if (t == 255) bsum[blockIdx.x] = lds[255];
  int e0 = excl, e1 = e0 + v.x, e2 = e1 + v.y, e3 = e2 + v.z;
  if (base < n) out[base] = e0;
  if (base + 1 < n) out[base + 1] = e1;
  if (base + 2 < n) out[base + 2] = e2;
  if (base + 3 < n) out[base + 3] = e3;
}

__global__ void scan2_kernel(int* __restrict__ bsum, int nb) {   // nb <= 128
  __shared__ int lds[128];
  int t = threadIdx.x;
  int v = (t < nb) ? bsum[t] : 0;
  lds[t] = v;
  __syncthreads();
  for (int o = 1; o < 128; o <<= 1) {
    int a = (t >= o) ? lds[t - o] : 0;
    __syncthreads();
    lds[t] += a;
    __syncthreads();
  }
  if (t < nb) bsum[t] = lds[t] - v;   // exclusive
}

__global__ void scan3_kernel(int* __restrict__ out, const int* __restrict__ bsum,
                             int n, int total) {
  int g = blockIdx.x * 256 + threadIdx.x;
  if (g == 0) out[n] = total;
  int base = g * 4;
  if (base >= n) return;
  int add = bsum[base / TS];
  if (base + 3 < n) {
    int4 v = *reinterpret_cast<int4*>(out + base);
    v.x += add; v.y += add; v.z += add; v.w += add;
    *reinterpret_cast<int4*>(out + base) = v;
  } else {
    for (int q = 0; q < 4 && base + q < n; ++q) out[base + q] += add;
  }
}

__global__ void fill_kernel(const int* __restrict__ ei, const int* __restrict__ ea,
                            const int* __restrict__ offs, int* __restrict__ fillc,
                            int* __restrict__ perm, int E) {
  int e = blockIdx.x * 256 + threadIdx.x;
  if (e >= E) return;
  int key = ei[E + e] * 5 + ea[e];
  int p = atomicAdd(&fillc[key], 1);
  perm[offs[key] + p] = ei[e];   // store src
}

// ---------------- gather kernels (no atomics) ----------------

__global__ void gather1_kernel(const unsigned short* __restrict__ xb, const int* __restrict__ offs,
                               const int* __restrict__ perm, unsigned short* __restrict__ meanb5) {
  int i = blockIdx.x;
  int k = blockIdx.y;
  int t = threadIdx.x;
  int b0 = offs[i * 5 + k], b1 = offs[i * 5 + k + 1];
  float a0 = 0.f, a1 = 0.f, a2 = 0.f, a3 = 0.f;
  for (int e = b0; e < b1; ++e) {
    int s = perm[e];
    ushort4 v = reinterpret_cast<const ushort4*>(xb + (size_t)s * 512)[t];
    a0 += bf2f(v.x); a1 += bf2f(v.y); a2 += bf2f(v.z); a3 += bf2f(v.w);
  }
  float inv = (b1 > b0) ? 1.0f / (float)(b1 - b0) : 0.0f;
  pack4(meanb5 + (size_t)i * CATW + k * 512 + t * 4, a0 * inv, a1 * inv, a2 * inv, a3 * inv);
}

__global__ void gather2_kernel(const float* __restrict__ z, const int* __restrict__ offs,
                               const int* __restrict__ perm, float* __restrict__ mean2) {
  int i = blockIdx.x;
  int t = threadIdx.x;
  int b0 = offs[i * 5], b1 = offs[i * 5 + 5];
  float4 acc = make_float4(0.f, 0.f, 0.f, 0.f);
  for (int e = b0; e < b1; ++e) {
    int s = perm[e];
    float4 v = reinterpret_cast<const float4*>(z + (size_t)s * 512)[t];
    acc.x += v.x; acc.y += v.y; acc.z += v.z; acc.w += v.w;
  }
  float inv = (b1 > b0) ? 1.0f / (float)(b1 - b0) : 1.0f;
  reinterpret_cast<float4*>(mean2 + (size_t)i * 512)[t] =
      make_float4(acc.x * inv, acc.y * inv, acc.z * inv, acc.w * inv);
}

// d_out += mean2 + bias   (mu half / logvar half)
__global__ void add_kernel(float* __restrict__ dout, const float* __restrict__ mean2,
                           const float* __restrict__ bmu, const float* __restrict__ blv,
                           int M, int n4) {
  int g = blockIdx.x * 256 + threadIdx.x;
  if (g >= n4) return;
  int base = g * 4;
  int i = base >> 9;
  int c = base & 511;
  float4 m2 = *reinterpret_cast<const float4*>(mean2 + (size_t)i * 512 + c);
  int cc = c & 255;
  float* op;
  const float* bp;
  if (c < 256) { op = dout + (size_t)i * OUTW + cc; bp = bmu + cc; }
  else         { op = dout + (size_t)M * OUTW + (size_t)i * OUTW + cc; bp = blv + cc; }
  float4 y = *reinterpret_cast<float4*>(op);
  float4 b = *reinterpret_cast<const float4*>(bp);
  y.x += m2.x + b.x; y.y += m2.y + b.y; y.z += m2.z + b.z; y.w += m2.w + b.w;
  *reinterpret_cast<float4*>(op) = y;
}

// ---------------- MFMA GEMM: BM=BN=256, BK=64, 8 waves, 2-slot dbuf, race-free ----------
// C[i][j] = sum_k A[i][k] * B[j][k]   (B row-major, K contiguous)
// Traffic argument: operand bytes moved from L2/L3 scale as (1/BM+1/BN); 256^2 halves the
// 128^2 tiles' 1.6GB -> 0.8GB per big GEMM (the measured r6..r11 ~196us invariant).
// Race-free schedule: during K-tile t, READS touch only slot t&1; WRITES (staging t+1)
// touch only slot (t+1)&1. One __syncthreads() per K-tile: its vmcnt drain lands tile
// t+1 (issued one full compute-tile earlier, ~1400cyc lead) and separates the last read
// of slot s from its next overwrite. Provably no overlapping access windows.
// LDS swizzle: linear dest + source k-chunk (l&7)^(l>>3); read chunk^(row&7)
// (both-sides involution; r7/r8 measured SQ_LDS_BANK_CONFLICT = 0 with this scheme).
// MODE 0: z=blockIdx.z; A=[meanb5 z-chunk | xb] (K=1024), B=w1[z]; bias->ReLU->BN -> hb
// MODE 1: A=hb (K=2560), B=w23; j<512 -> zbuf f32; j>=512 -> d_out raw
template<int MODE>
__global__ __launch_bounds__(512, 2)
void gemm_kernel(const unsigned short* __restrict__ A,
                 const unsigned short* __restrict__ A2,
                 const unsigned short* __restrict__ B,
                 unsigned short* __restrict__ hOut,
                 float* __restrict__ fOut,
                 float* __restrict__ fOut2,
                 const float* __restrict__ p0,   // MODE0: bl5
                 const float* __restrict__ p1,   // MODE0: rmean
                 const float* __restrict__ p2,   // MODE0: rvar
                 const float* __restrict__ p3,   // MODE0: gamma
                 const float* __restrict__ p4,   // MODE0: beta
                 int M)
{
  constexpr int KTOT = (MODE == 0) ? (2 * INCH) : CATW;
  constexpr int NTK = KTOT / 64;             // 16 / 40 K-tiles
  constexpr int NBLK = (MODE == 0) ? 2 : 4;  // 256-col tiles

  // bijective XCD-chunked swizzle (m204), col-fastest within an XCD chunk
  const int nwg = gridDim.x;
  const int o = blockIdx.x;
  const int q = nwg >> 3, r = nwg & 7;
  const int xcd = o & 7;
  const int wg = (xcd < r ? xcd * (q + 1) : r * (q + 1) + (xcd - r) * q) + (o >> 3);
  const int rowBase = (wg / NBLK) * 256;
  const int nBase = (wg % NBLK) * 256;
  const int z = (MODE == 0) ? blockIdx.z : 0;
  const int bRow0 = (MODE == 0) ? (z * 512 + nBase) : nBase;

  __shared__ unsigned short Lds[2][2][16384];   // [slot][A/B][256 rows x 64 k], 128KB

  const int tid = threadIdx.x;
  const int lane = tid & 63;
  const int wv = tid >> 6;                  // 0..7
  const int wm = wv >> 2, wn = wv & 3;      // 2M x 4N wave grid; per-wave C = 128x64
  const int lr = lane & 15, kg = lane >> 4;
  const int lrow8 = lane >> 3;              // 0..7
  const int kswz = ((lane & 7) ^ lrow8) * 8;  // inverse swizzle at global source

  f32x4 acc[8][4] = {};

  // stage K-tile kt into slot: wave wv stages A rows [wv*32,+32) and B cols [wv*32,+32)
  // as 4 chunks each (8 rows x 64 k = 1KB per gload_lds).
  auto stage = [&](int slot, int kt) {
    const int kk0 = kt * 64;
#pragma unroll
    for (int c = 0; c < 4; ++c) {
      const int rloc = wv * 32 + c * 8;
      int grow = rowBase + rloc + lrow8;
      if (grow >= M) grow = M - 1;
      const unsigned short* src;
      if (MODE == 0) {
        if (kk0 < INCH) src = A + (size_t)grow * CATW + z * 512 + kk0 + kswz;
        else            src = A2 + (size_t)grow * INCH + (kk0 - INCH) + kswz;
      } else {
        src = A + (size_t)grow * KTOT + kk0 + kswz;
      }
      __builtin_amdgcn_global_load_lds((const void*)src,
          (void*)&Lds[slot][0][rloc * 64], 16, 0, 0);
    }
#pragma unroll
    for (int c = 0; c < 4; ++c) {
      const int rloc = wv * 32 + c * 8;
      const int gcol = bRow0 + rloc + lrow8;
      const unsigned short* src = B + (size_t)gcol * KTOT + kk0 + kswz;
      __builtin_amdgcn_global_load_lds((const void*)src,
          (void*)&Lds[slot][1][rloc * 64], 16, 0, 0);
    }
  };

  auto compute = [&](int slot) {
#pragma unroll
    for (int ks = 0; ks < 2; ++ks) {
      bf16x8 bv[4];
#pragma unroll
      for (int n = 0; n < 4; ++n) {
        const int col = wn * 64 + n * 16 + lr;
        bv[n] = *reinterpret_cast<const bf16x8*>(
            &Lds[slot][1][col * 64 + (((ks * 4 + kg) ^ (col & 7)) * 8)]);
      }
#pragma unroll
      for (int fm = 0; fm < 8; ++fm) {
        const int row = wm * 128 + fm * 16 + lr;
        bf16x8 av = *reinterpret_cast<const bf16x8*>(
            &Lds[slot][0][row * 64 + (((ks * 4 + kg) ^ (row & 7)) * 8)]);
#pragma unroll
        for (int n = 0; n < 4; ++n)
          acc[fm][n] = __builtin_amdgcn_mfma_f32_16x16x32_bf16(av, bv[n], acc[fm][n], 0, 0, 0);
      }
    }
  };

  // ---- main loop: 1 barrier per K-tile; strict alternate-slot staging
  stage(0, 0);
  __syncthreads();                          // tile 0 landed
  for (int t = 0; t < NTK; ++t) {
    const int slot = t & 1;
    if (t + 1 < NTK) stage(slot ^ 1, t + 1);   // writes only the other slot
    compute(slot);                             // reads only this slot
    __syncthreads();                           // drains tile t+1 loads; read/write separation
  }

  // ---- epilogue (r12-verified index math)
#pragma unroll
  for (int n = 0; n < 4; ++n) {
    const int j = nBase + wn * 64 + n * 16 + lr;
    if (MODE == 0) {
      const int ch = z * 512 + j;
      const float bias = p0[ch];
      const float scale = rsqrtf(p2[ch] + BN_EPS) * p3[ch];
      const float rm = p1[ch], be = p4[ch];
#pragma unroll
      for (int fm = 0; fm < 8; ++fm) {
        const int ib = rowBase + wm * 128 + fm * 16 + kg * 4;
#pragma unroll
        for (int rr = 0; rr < 4; ++rr) {
          const int i = ib + rr;
          if (i < M) {
            float v = acc[fm][n][rr] + bias;  // SAGE output
            v = fmaxf(v, 0.0f);               // ReLU FIRST (reference order)
            v = (v - rm) * scale + be;        // BN SECOND
            hOut[(size_t)i * CATW + ch] = f2bf(v);
          }
        }
      }
    } else {
#pragma unroll
      for (int fm = 0; fm < 8; ++fm) {
        const int ib = rowBase + wm * 128 + fm * 16 + kg * 4;
#pragma unroll
        for (int rr = 0; rr < 4; ++rr) {
          const int i = ib + rr;
          if (i < M) {
            const float v = acc[fm][n][rr];
            if (j < 512) {
              fOut[(size_t)i * 512 + j] = v;                 // zbuf
            } else {
              const int jj = j - 512;
              size_t o2 = (jj < OUTW) ? ((size_t)i * OUTW + jj)
                                      : ((size_t)M * OUTW + (size_t)i * OUTW + (jj - OUTW));
              fOut2[o2] = v;                                 // y3 (raw, bias added later)
            }
          }
        }
      }
    }
  }
}

// ---------------- launch ----------------

extern "C" void kernel_launch(void* const* d_in, const int* in_sizes, int n_in,
                              void* d_out, int out_size, void* d_ws, size_t ws_size,
                              hipStream_t stream) {
  const float* x     = (const float*)d_in[0];
  const int*   ei    = (const int*)d_in[1];
  const int*   ea    = (const int*)d_in[2];
  const float* Wl5   = (const float*)d_in[3];
  const float* Wr5   = (const float*)d_in[4];
  const float* bl5   = (const float*)d_in[5];
  const float* Wmu_l = (const float*)d_in[6];
  const float* Wmu_r = (const float*)d_in[7];
  const float* bmu   = (const float*)d_in[8];
  const float* Wlv_l = (const float*)d_in[9];
  const float* Wlv_r = (const float*)d_in[10];
  const float* blv   = (const float*)d_in[11];
  const float* gamma = (const float*)d_in[12];
  const float* beta  = (const float*)d_in[13];
  const float* rmean = (const float*)d_in[14];
  const float* rvar  = (const float*)d_in[15];
  (void)n_in; (void)out_size;

  const int N = in_sizes[0] / INCH;   // 20000
  const int E = in_sizes[2];          // 100000
  const int NKEY = N * 5;

  // ---- workspace layout (~243 MB) ----
  char* ws = (char*)d_ws;
  size_t off = 0;
  auto take = [&](size_t bytes) { char* p = ws + off; off += (bytes + 255) & ~(size_t)255; return p; };
  unsigned short* hb = (unsigned short*)take((size_t)N * CATW * 2);      // 102.4 MB
  char* U = take((size_t)N * CATW * 2);                                  // 102.4 MB: meanb5, later zbuf+mean2
  unsigned short* xb = (unsigned short*)take((size_t)N * 512 * 2);       // 20.5 MB
  unsigned short* w1  = (unsigned short*)take((size_t)5 * 512 * 1024 * 2);
  unsigned short* w23 = (unsigned short*)take((size_t)1024 * CATW * 2);  // [w2;w3] row-major
  int* cntk  = (int*)take((size_t)NKEY * 4);
  int* offs  = (int*)take((size_t)(NKEY + 1) * 4);
  int* fillc = (int*)take((size_t)NKEY * 4);
  int* perm  = (int*)take((size_t)E * 4);
  int* bsum  = (int*)take(256 * 4);
  if (off > ws_size) return;  // diagnostic guard -> clean absmax-488 failure

  unsigned short* meanb5 = (unsigned short*)U;         // [N,5,512] bf16 (layer-1 life)
  float* zbuf  = (float*)U;                            // [N,512] f32 (layer-2 life)
  float* mean2 = (float*)(U + (size_t)N * 512 * 4);    // [N,512] f32

  // conversions / packing
  cvt_bf16_kernel<<<dim3((N * INCH / 4 + 255) / 256), 256, 0, stream>>>(x, xb, N * INCH / 4);
  pack_w1_kernel<<<dim3((5 * 512 * 1024 / 4 + 255) / 256), 256, 0, stream>>>(Wl5, Wr5, w1);
  pack_lr_kernel<<<dim3((512 * CATW / 4 + 255) / 256), 256, 0, stream>>>(Wmu_l, Wlv_l, w23);
  pack_lr_kernel<<<dim3((512 * CATW / 4 + 255) / 256), 256, 0, stream>>>(Wmu_r, Wlv_r,
                                                                         w23 + (size_t)512 * CATW);

  // CSR build: key = dst*5 + rel
  hipMemsetAsync(cntk, 0, (size_t)NKEY * 4, stream);
  hipMemsetAsync(fillc, 0, (size_t)NKEY * 4, stream);
  hist_kernel<<<dim3((E + 255) / 256), 256, 0, stream>>>(ei, ea, cntk, E);
  const int nb = (NKEY + TS - 1) / TS;
  scan1_kernel<<<dim3(nb), 256, 0, stream>>>(cntk, offs, bsum, NKEY);
  scan2_kernel<<<dim3(1), 128, 0, stream>>>(bsum, nb);
  scan3_kernel<<<dim3((NKEY / 4 + 255) / 256 + 1), 256, 0, stream>>>(offs, bsum, NKEY, E);
  fill_kernel<<<dim3((E + 255) / 256), 256, 0, stream>>>(ei, ea, offs, fillc, perm, E);

  // layer 1: all 5 relation means, then ONE batched GEMM dispatch (z = relation)
  gather1_kernel<<<dim3(N, 5), 128, 0, stream>>>(xb, offs, perm, meanb5);
  const int mblk = (N + 255) / 256;    // 79 row-tiles of 256
  gemm_kernel<0><<<dim3(mblk * 2, 1, 5), 512, 0, stream>>>(
      meanb5, xb, w1, hb, nullptr, nullptr,
      bl5, rmean, rvar, gamma, beta, N);

  // layer 2: one pass over hb computes z (->zbuf) and y3 (->d_out)
  gemm_kernel<1><<<dim3(mblk * 4, 1, 1), 512, 0, stream>>>(
      hb, nullptr, w23, nullptr, zbuf, (float*)d_out,
      nullptr, nullptr, nullptr, nullptr, nullptr, N);

  gather2_kernel<<<dim3(N), 128, 0, stream>>>(zbuf, offs, perm, mean2);

  add_kernel<<<dim3((N * 512 / 4 + 255) / 256), 256, 0, stream>>>(
      (float*)d_out, mean2, bmu, blv, N, N * 512 / 4);
}

// Round 14
// 435.845 us; speedup vs baseline: 1.0267x; 1.0267x over previous
//
#include <hip/hip_runtime.h>
#include <stdint.h>

#define INCH 512
#define HIDW 512
#define CATW 2560
#define OUTW 256
#define BN_EPS 1e-5f
#define TS 1024   // scan tile

typedef __bf16 bf16x8 __attribute__((ext_vector_type(8)));
typedef float f32x4 __attribute__((ext_vector_type(4)));

__device__ __forceinline__ unsigned short f2bf(float f) {
  union { float f; unsigned u; } v; v.f = f;
  unsigned r = v.u + 0x7FFFu + ((v.u >> 16) & 1u);   // RNE
  return (unsigned short)(r >> 16);
}

__device__ __forceinline__ float bf2f(unsigned short u) {
  union { unsigned u; float f; } v; v.u = ((unsigned)u) << 16; return v.f;
}

__device__ __forceinline__ void pack4(unsigned short* dst, float a, float b, float c, float d) {
  unsigned lo = (unsigned)f2bf(a) | ((unsigned)f2bf(b) << 16);
  unsigned hi = (unsigned)f2bf(c) | ((unsigned)f2bf(d) << 16);
  *reinterpret_cast<uint2*>(dst) = make_uint2(lo, hi);
}

// ---------------- conversion / packing kernels ----------------

__global__ void cvt_bf16_kernel(const float* __restrict__ in, unsigned short* __restrict__ out, int n4) {
  int g = blockIdx.x * blockDim.x + threadIdx.x;
  if (g >= n4) return;
  int base = g * 4;
  float4 v = *reinterpret_cast<const float4*>(in + base);
  pack4(out + base, v.x, v.y, v.z, v.w);
}

// w1p fragment-order: elem ((z*128 + c)*512 + j)*8 + e  =  W1[z][j][c*8+e]
// where W1[z][j][k] = k<512 ? Wl5[z][j][k] : Wr5[z][j][k-512]
__global__ void pack_w1p_kernel(const float* __restrict__ Wl, const float* __restrict__ Wr,
                                unsigned short* __restrict__ out) {
  int g = blockIdx.x * blockDim.x + threadIdx.x;
  if (g >= 5 * 128 * 512) return;
  int z = g >> 16;              // /65536
  int rem = g & 65535;
  int c = rem >> 9;             // 0..127
  int j = rem & 511;
  int kk = c * 8;
  const float* src = (kk < 512) ? (Wl + ((size_t)(z * 512 + j)) * 512 + kk)
                                : (Wr + ((size_t)(z * 512 + j)) * 512 + (kk - 512));
  float4 a = *reinterpret_cast<const float4*>(src);
  float4 b = *reinterpret_cast<const float4*>(src + 4);
  pack4(out + (size_t)g * 8, a.x, a.y, a.z, a.w);
  pack4(out + (size_t)g * 8 + 4, b.x, b.y, b.z, b.w);
}

// w23p fragment-order: elem (c*1024 + j)*8 + e = W23[j][c*8+e]
// W23 rows: [Wmu_l(256); Wlv_l(256); Wmu_r(256); Wlv_r(256)], K=2560
__global__ void pack_w23p_kernel(const float* __restrict__ Wmu_l, const float* __restrict__ Wlv_l,
                                 const float* __restrict__ Wmu_r, const float* __restrict__ Wlv_r,
                                 unsigned short* __restrict__ out) {
  int g = blockIdx.x * blockDim.x + threadIdx.x;
  if (g >= 320 * 1024) return;
  int c = g >> 10;              // 0..319
  int j = g & 1023;
  const float* row;
  if (j < 256)       row = Wmu_l + (size_t)j * CATW;
  else if (j < 512)  row = Wlv_l + (size_t)(j - 256) * CATW;
  else if (j < 768)  row = Wmu_r + (size_t)(j - 512) * CATW;
  else               row = Wlv_r + (size_t)(j - 768) * CATW;
  const float* src = row + c * 8;
  float4 a = *reinterpret_cast<const float4*>(src);
  float4 b = *reinterpret_cast<const float4*>(src + 4);
  pack4(out + (size_t)g * 8, a.x, a.y, a.z, a.w);
  pack4(out + (size_t)g * 8 + 4, b.x, b.y, b.z, b.w);
}

// ---------------- CSR build: key = dst*5 + rel ----------------

__global__ void hist_kernel(const int* __restrict__ ei, const int* __restrict__ ea,
                            int* __restrict__ cnt, int E) {
  int e = blockIdx.x * 256 + threadIdx.x;
  if (e >= E) return;
  atomicAdd(&cnt[ei[E + e] * 5 + ea[e]], 1);
}

__global__ void scan1_kernel(const int* __restrict__ in, int* __restrict__ out,
                             int* __restrict__ bsum, int n) {
  __shared__ int lds[256];
  int t = threadIdx.x;
  int base = blockIdx.x * TS + t * 4;
  int4 v = make_int4(0, 0, 0, 0);
  if (base + 3 < n) v = *reinterpret_cast<const int4*>(in + base);
  else {
    if (base < n) v.x = in[base];
    if (base + 1 < n) v.y = in[base + 1];
    if (base + 2 < n) v.z = in[base + 2];
    if (base + 3 < n) v.w = in[base + 3];
  }
  int s = v.x + v.y + v.z + v.w;
  lds[t] = s;
  __syncthreads();
  for (int o = 1; o < 256; o <<= 1) {
    int a = (t >= o) ? lds[t - o] : 0;
    __syncthreads();
    lds[t] += a;
    __syncthreads();
  }
  int excl = lds[t] - s;
  if (t == 255) bsum[blockIdx.x] = lds[255];
  int e0 = excl, e1 = e0 + v.x, e2 = e1 + v.y, e3 = e2 + v.z;
  if (base < n) out[base] = e0;
  if (base + 1 < n) out[base + 1] = e1;
  if (base + 2 < n) out[base + 2] = e2;
  if (base + 3 < n) out[base + 3] = e3;
}

__global__ void scan2_kernel(int* __restrict__ bsum, int nb) {   // nb <= 128
  __shared__ int lds[128];
  int t = threadIdx.x;
  int v = (t < nb) ? bsum[t] : 0;
  lds[t] = v;
  __syncthreads();
  for (int o = 1; o < 128; o <<= 1) {
    int a = (t >= o) ? lds[t - o] : 0;
    __syncthreads();
    lds[t] += a;
    __syncthreads();
  }
  if (t < nb) bsum[t] = lds[t] - v;   // exclusive
}

__global__ void scan3_kernel(int* __restrict__ out, const int* __restrict__ bsum,
                             int n, int total) {
  int g = blockIdx.x * 256 + threadIdx.x;
  if (g == 0) out[n] = total;
  int base = g * 4;
  if (base >= n) return;
  int add = bsum[base / TS];
  if (base + 3 < n) {
    int4 v = *reinterpret_cast<int4*>(out + base);
    v.x += add; v.y += add; v.z += add; v.w += add;
    *reinterpret_cast<int4*>(out + base) = v;
  } else {
    for (int q = 0; q < 4 && base + q < n; ++q) out[base + q] += add;
  }
}

__global__ void fill_kernel(const int* __restrict__ ei, const int* __restrict__ ea,
                            const int* __restrict__ offs, int* __restrict__ fillc,
                            int* __restrict__ perm, int E) {
  int e = blockIdx.x * 256 + threadIdx.x;
  if (e >= E) return;
  int key = ei[E + e] * 5 + ea[e];
  int p = atomicAdd(&fillc[key], 1);
  perm[offs[key] + p] = ei[e];   // store src
}

// ---------------- gather kernels (no atomics) ----------------

__global__ void gather1_kernel(const unsigned short* __restrict__ xb, const int* __restrict__ offs,
                               const int* __restrict__ perm, unsigned short* __restrict__ meanb5) {
  int i = blockIdx.x;
  int k = blockIdx.y;
  int t = threadIdx.x;
  int b0 = offs[i * 5 + k], b1 = offs[i * 5 + k + 1];
  float a0 = 0.f, a1 = 0.f, a2 = 0.f, a3 = 0.f;
  for (int e = b0; e < b1; ++e) {
    int s = perm[e];
    ushort4 v = reinterpret_cast<const ushort4*>(xb + (size_t)s * 512)[t];
    a0 += bf2f(v.x); a1 += bf2f(v.y); a2 += bf2f(v.z); a3 += bf2f(v.w);
  }
  float inv = (b1 > b0) ? 1.0f / (float)(b1 - b0) : 0.0f;
  pack4(meanb5 + (size_t)i * CATW + k * 512 + t * 4, a0 * inv, a1 * inv, a2 * inv, a3 * inv);
}

__global__ void gather2_kernel(const float* __restrict__ z, const int* __restrict__ offs,
                               const int* __restrict__ perm, float* __restrict__ mean2) {
  int i = blockIdx.x;
  int t = threadIdx.x;
  int b0 = offs[i * 5], b1 = offs[i * 5 + 5];
  float4 acc = make_float4(0.f, 0.f, 0.f, 0.f);
  for (int e = b0; e < b1; ++e) {
    int s = perm[e];
    float4 v = reinterpret_cast<const float4*>(z + (size_t)s * 512)[t];
    acc.x += v.x; acc.y += v.y; acc.z += v.z; acc.w += v.w;
  }
  float inv = (b1 > b0) ? 1.0f / (float)(b1 - b0) : 1.0f;
  reinterpret_cast<float4*>(mean2 + (size_t)i * 512)[t] =
      make_float4(acc.x * inv, acc.y * inv, acc.z * inv, acc.w * inv);
}

// d_out += mean2 + bias   (mu half / logvar half)
__global__ void add_kernel(float* __restrict__ dout, const float* __restrict__ mean2,
                           const float* __restrict__ bmu, const float* __restrict__ blv,
                           int M, int n4) {
  int g = blockIdx.x * 256 + threadIdx.x;
  if (g >= n4) return;
  int base = g * 4;
  int i = base >> 9;
  int c = base & 511;
  float4 m2 = *reinterpret_cast<const float4*>(mean2 + (size_t)i * 512 + c);
  int cc = c & 255;
  float* op;
  const float* bp;
  if (c < 256) { op = dout + (size_t)i * OUTW + cc; bp = bmu + cc; }
  else         { op = dout + (size_t)M * OUTW + (size_t)i * OUTW + cc; bp = blv + cc; }
  float4 y = *reinterpret_cast<float4*>(op);
  float4 b = *reinterpret_cast<const float4*>(bp);
  y.x += m2.x + b.x; y.y += m2.y + b.y; y.z += m2.z + b.z; y.w += m2.w + b.w;
  *reinterpret_cast<float4*>(op) = y;
}

// ---------------- MFMA GEMM: 128x128, BK=32, 4 waves, A 4-slot LDS ring (3 tiles ahead),
// B direct global->reg ping-pong, RAW s_barrier (no vmcnt drain) ----------------
// MLP fix vs r11: per step t issue loadB(t+1) THEN stageA(t+3). Compiler's pre-MFMA wait
// for B(t) is vmcnt(8) (newer: stage(t+2),B(t+1),stage(t+3)), retiring {B(t),stage(t+1)}.
// => stage(s) retired at step s-1, issued at step s-3: 2-3 step (~1200-1800cy) latency lead
// for the L3/HBM A-stream, vs ~600cy in all prior structures (the measured invariant).
// Slot-reuse race-free: stage(t+3) writes slot (t-1)&3, whose reads completed before the
// barrier ending step t-1 (lgkmcnt before MFMA); write issued after that barrier.
// MODE 0: z=blockIdx.z; A=[meanb5 z-chunk | xb] (K=1024), B=w1p[z]; bias->ReLU->BN -> hb
// MODE 1: A=hb (K=2560), B=w23p; j<512 -> zbuf f32; j>=512 -> d_out raw
template<int MODE>
__global__ __launch_bounds__(256, 3)
void gemm_kernel(const unsigned short* __restrict__ A,
                 const unsigned short* __restrict__ A2,
                 const unsigned short* __restrict__ B,
                 unsigned short* __restrict__ hOut,
                 float* __restrict__ fOut,
                 float* __restrict__ fOut2,
                 const float* __restrict__ p0,   // MODE0: bl5
                 const float* __restrict__ p1,   // MODE0: rmean
                 const float* __restrict__ p2,   // MODE0: rvar
                 const float* __restrict__ p3,   // MODE0: gamma
                 const float* __restrict__ p4,   // MODE0: beta
                 int M)
{
  constexpr int KTOT = (MODE == 0) ? (2 * INCH) : CATW;
  constexpr int KT = KTOT / 32;              // 32 / 80 (even)
  constexpr int NBLK = (MODE == 0) ? 4 : 8;  // output cols / 128
  constexpr int NC = (MODE == 0) ? 512 : 1024;   // B col count (fragment-order)

  // bijective XCD-chunked swizzle (m204), col-fastest within an XCD chunk
  const int nwg = gridDim.x;
  const int o = blockIdx.x;
  const int q = nwg >> 3, r = nwg & 7;
  const int xcd = o & 7;
  const int wg = (xcd < r ? xcd * (q + 1) : r * (q + 1) + (xcd - r) * q) + (o >> 3);
  const int rowBase = (wg / NBLK) * 128;
  const int nBase = (wg % NBLK) * 128;
  const int z = (MODE == 0) ? blockIdx.z : 0;
  const unsigned short* BpF = (MODE == 0) ? (B + (size_t)z * 524288) : B;  // z*128*512*8

  __shared__ unsigned short As[4][4096];   // 4-slot ring x [128 rows][32 k] bf16, 32KB

  const int tid = threadIdx.x;
  const int lane = tid & 63;
  const int wv = tid >> 6;                 // 0..3
  const int wr = wv >> 1, wc = wv & 1;
  const int lr = lane & 15, kg = lane >> 4;

  // ---- A staging (r10 geometry): wave wv stages chunks {2wv,2wv+1},
  // chunk = 16 rows x 32 k = 1KB; lane l -> row chunk*16+(l>>2), k-chunk (l&3)^((l>>4)&3).
  const int srow0 = (wv * 2) * 16 + (lane >> 2);
  const int srow1 = srow0 + 16;
  const int kswz = (((lane & 3) ^ ((lane >> 4) & 3)) * 8);   // elements
  int gar0 = rowBase + srow0; if (gar0 >= M) gar0 = M - 1;
  int gar1 = rowBase + srow1; if (gar1 >= M) gar1 = M - 1;

  // ---- A fragment read slots: ar*32 + ((kg ^ ((lr>>2)&3))*8)  (involution pair w/ kswz)
  int aslot[4];
#pragma unroll
  for (int m = 0; m < 4; ++m) {
    const int ar = wr * 64 + m * 16 + lr;
    aslot[m] = ar * 32 + ((kg ^ ((lr >> 2) & 3)) * 8);
  }

  // ---- B fragment-order offsets: elem ((c*NC) + j)*8, c = kt*4+kg, j = col row
  size_t bjoff[4];
#pragma unroll
  for (int n = 0; n < 4; ++n)
    bjoff[n] = (size_t)(nBase + wc * 64 + n * 16 + lr) * 8;

  f32x4 acc[4][4] = {};

  auto stageA = [&](int slot, int kt) {
    const int kk0 = kt * 32;
    const unsigned short *a0p, *a1p;
    if (MODE == 0) {
      if (kk0 < INCH) {
        a0p = A + (size_t)gar0 * CATW + z * 512 + kk0 + kswz;
        a1p = A + (size_t)gar1 * CATW + z * 512 + kk0 + kswz;
      } else {
        a0p = A2 + (size_t)gar0 * INCH + (kk0 - INCH) + kswz;
        a1p = A2 + (size_t)gar1 * INCH + (kk0 - INCH) + kswz;
      }
    } else {
      a0p = A + (size_t)gar0 * KTOT + kk0 + kswz;
      a1p = A + (size_t)gar1 * KTOT + kk0 + kswz;
    }
    __builtin_amdgcn_global_load_lds((const void*)a0p, (void*)&As[slot][(wv * 2) * 512], 16, 0, 0);
    __builtin_amdgcn_global_load_lds((const void*)a1p, (void*)&As[slot][(wv * 2 + 1) * 512], 16, 0, 0);
  };

  auto loadB = [&](int kt, bf16x8 (&dst)[4]) {
    const size_t cbase = (size_t)((kt << 2) + kg) * NC * 8;
#pragma unroll
    for (int n = 0; n < 4; ++n)
      dst[n] = *reinterpret_cast<const bf16x8*>(BpF + cbase + bjoff[n]);
  };

  // one step: ds_read A(t) | loadB(t+1) | stageA(t+3) | MFMA(t) | raw s_barrier
  auto step = [&](int t, const bf16x8 (&bcur)[4], bf16x8 (&bnxt)[4]) {
    const int slot = t & 3;
    bf16x8 af[4];
#pragma unroll
    for (int m = 0; m < 4; ++m)
      af[m] = *reinterpret_cast<const bf16x8*>(&As[slot][aslot[m]]);
    if (t + 1 < KT) loadB(t + 1, bnxt);           // B first (older than stage(t+3))
    if (t + 3 < KT) stageA((t + 3) & 3, t + 3);   // 3-deep A prefetch
    __builtin_amdgcn_sched_barrier(0);
    __builtin_amdgcn_s_setprio(1);
#pragma unroll
    for (int m = 0; m < 4; ++m)
#pragma unroll
      for (int n = 0; n < 4; ++n)
        acc[m][n] = __builtin_amdgcn_mfma_f32_16x16x32_bf16(af[m], bcur[n], acc[m][n], 0, 0, 0);
    __builtin_amdgcn_s_setprio(0);
    __builtin_amdgcn_sched_barrier(0);
    __builtin_amdgcn_s_barrier();       // raw barrier: NO vmcnt drain
    __builtin_amdgcn_sched_barrier(0);
  };

  // ---- prologue: A(0..2) staged; B(0) in regs; wait A(0) only (8 newer in flight)
  bf16x8 bP[4], bQ[4];
  stageA(0, 0);
  stageA(1, 1);
  stageA(2, 2);
  __builtin_amdgcn_sched_barrier(0);
  loadB(0, bP);
  __builtin_amdgcn_sched_barrier(0);
  asm volatile("s_waitcnt vmcnt(8)" ::: "memory");   // A(0) landed; A(1),A(2),B(0) in flight
  __builtin_amdgcn_s_barrier();
  __builtin_amdgcn_sched_barrier(0);

  for (int t = 0; t < KT; t += 2) {   // KT even
    step(t, bP, bQ);
    step(t + 1, bQ, bP);
  }

  // ---- epilogue (r10/r11-verified)
#pragma unroll
  for (int n = 0; n < 4; ++n) {
    const int j = nBase + wc * 64 + n * 16 + lr;
    if (MODE == 0) {
      const int ch = z * 512 + j;
      const float bias = p0[ch];
      const float scale = rsqrtf(p2[ch] + BN_EPS) * p3[ch];
      const float rm = p1[ch], be = p4[ch];
#pragma unroll
      for (int m = 0; m < 4; ++m) {
        const int ib = rowBase + wr * 64 + m * 16 + kg * 4;
#pragma unroll
        for (int rr = 0; rr < 4; ++rr) {
          const int i = ib + rr;
          if (i < M) {
            float v = acc[m][n][rr] + bias;   // SAGE output
            v = fmaxf(v, 0.0f);               // ReLU FIRST (reference order)
            v = (v - rm) * scale + be;        // BN SECOND
            hOut[(size_t)i * CATW + ch] = f2bf(v);
          }
        }
      }
    } else {
#pragma unroll
      for (int m = 0; m < 4; ++m) {
        const int ib = rowBase + wr * 64 + m * 16 + kg * 4;
#pragma unroll
        for (int rr = 0; rr < 4; ++rr) {
          const int i = ib + rr;
          if (i < M) {
            const float v = acc[m][n][rr];
            if (j < 512) {
              fOut[(size_t)i * 512 + j] = v;                 // zbuf
            } else {
              const int jj = j - 512;
              size_t o2 = (jj < OUTW) ? ((size_t)i * OUTW + jj)
                                      : ((size_t)M * OUTW + (size_t)i * OUTW + (jj - OUTW));
              fOut2[o2] = v;                                 // y3 (raw, bias added later)
            }
          }
        }
      }
    }
  }
}

// ---------------- launch ----------------

extern "C" void kernel_launch(void* const* d_in, const int* in_sizes, int n_in,
                              void* d_out, int out_size, void* d_ws, size_t ws_size,
                              hipStream_t stream) {
  const float* x     = (const float*)d_in[0];
  const int*   ei    = (const int*)d_in[1];
  const int*   ea    = (const int*)d_in[2];
  const float* Wl5   = (const float*)d_in[3];
  const float* Wr5   = (const float*)d_in[4];
  const float* bl5   = (const float*)d_in[5];
  const float* Wmu_l = (const float*)d_in[6];
  const float* Wmu_r = (const float*)d_in[7];
  const float* bmu   = (const float*)d_in[8];
  const float* Wlv_l = (const float*)d_in[9];
  const float* Wlv_r = (const float*)d_in[10];
  const float* blv   = (const float*)d_in[11];
  const float* gamma = (const float*)d_in[12];
  const float* beta  = (const float*)d_in[13];
  const float* rmean = (const float*)d_in[14];
  const float* rvar  = (const float*)d_in[15];
  (void)n_in; (void)out_size;

  const int N = in_sizes[0] / INCH;   // 20000
  const int E = in_sizes[2];          // 100000
  const int NKEY = N * 5;

  // ---- workspace layout (~243 MB) ----
  char* ws = (char*)d_ws;
  size_t off = 0;
  auto take = [&](size_t bytes) { char* p = ws + off; off += (bytes + 255) & ~(size_t)255; return p; };
  unsigned short* hb = (unsigned short*)take((size_t)N * CATW * 2);      // 102.4 MB
  char* U = take((size_t)N * CATW * 2);                                  // 102.4 MB: meanb5, later zbuf+mean2
  unsigned short* xb = (unsigned short*)take((size_t)N * 512 * 2);       // 20.5 MB
  unsigned short* w1p  = (unsigned short*)take((size_t)5 * 128 * 512 * 8 * 2);  // 5.24 MB
  unsigned short* w23p = (unsigned short*)take((size_t)320 * 1024 * 8 * 2);     // 5.24 MB
  int* cntk  = (int*)take((size_t)NKEY * 4);
  int* offs  = (int*)take((size_t)(NKEY + 1) * 4);
  int* fillc = (int*)take((size_t)NKEY * 4);
  int* perm  = (int*)take((size_t)E * 4);
  int* bsum  = (int*)take(256 * 4);
  if (off > ws_size) return;  // diagnostic guard -> clean absmax-488 failure

  unsigned short* meanb5 = (unsigned short*)U;         // [N,5,512] bf16 (layer-1 life)
  float* zbuf  = (float*)U;                            // [N,512] f32 (layer-2 life)
  float* mean2 = (float*)(U + (size_t)N * 512 * 4);    // [N,512] f32

  // conversions / packing (fragment-order weights)
  cvt_bf16_kernel<<<dim3((N * INCH / 4 + 255) / 256), 256, 0, stream>>>(x, xb, N * INCH / 4);
  pack_w1p_kernel<<<dim3((5 * 128 * 512 + 255) / 256), 256, 0, stream>>>(Wl5, Wr5, w1p);
  pack_w23p_kernel<<<dim3((320 * 1024 + 255) / 256), 256, 0, stream>>>(Wmu_l, Wlv_l, Wmu_r, Wlv_r, w23p);

  // CSR build: key = dst*5 + rel
  hipMemsetAsync(cntk, 0, (size_t)NKEY * 4, stream);
  hipMemsetAsync(fillc, 0, (size_t)NKEY * 4, stream);
  hist_kernel<<<dim3((E + 255) / 256), 256, 0, stream>>>(ei, ea, cntk, E);
  const int nb = (NKEY + TS - 1) / TS;
  scan1_kernel<<<dim3(nb), 256, 0, stream>>>(cntk, offs, bsum, NKEY);
  scan2_kernel<<<dim3(1), 128, 0, stream>>>(bsum, nb);
  scan3_kernel<<<dim3((NKEY / 4 + 255) / 256 + 1), 256, 0, stream>>>(offs, bsum, NKEY, E);
  fill_kernel<<<dim3((E + 255) / 256), 256, 0, stream>>>(ei, ea, offs, fillc, perm, E);

  // layer 1: all 5 relation means, then ONE batched GEMM dispatch (z = relation)
  gather1_kernel<<<dim3(N, 5), 128, 0, stream>>>(xb, offs, perm, meanb5);
  const int mblk = (N + 127) / 128;    // 157 row-tiles of 128
  gemm_kernel<0><<<dim3(mblk * 4, 1, 5), 256, 0, stream>>>(
      meanb5, xb, w1p, hb, nullptr, nullptr,
      bl5, rmean, rvar, gamma, beta, N);

  // layer 2: one pass over hb computes z (->zbuf) and y3 (->d_out)
  gemm_kernel<1><<<dim3(mblk * 8, 1, 1), 256, 0, stream>>>(
      hb, nullptr, w23p, nullptr, zbuf, (float*)d_out,
      nullptr, nullptr, nullptr, nullptr, nullptr, N);

  gather2_kernel<<<dim3(N), 128, 0, stream>>>(zbuf, offs, perm, mean2);

  add_kernel<<<dim3((N * 512 / 4 + 255) / 256), 256, 0, stream>>>(
      (float*)d_out, mean2, bmu, blv, N, N * 512 / 4);
}

// Round 15
// 368.907 us; speedup vs baseline: 1.2130x; 1.1814x over previous
//
#include <hip/hip_runtime.h>
#include <stdint.h>

#define INCH 512
#define HIDW 512
#define CATW 2560
#define OUTW 256
#define BN_EPS 1e-5f
#define TS 1024   // scan tile

typedef __bf16 bf16x8 __attribute__((ext_vector_type(8)));
typedef float f32x4 __attribute__((ext_vector_type(4)));

__device__ __forceinline__ unsigned short f2bf(float f) {
  union { float f; unsigned u; } v; v.f = f;
  unsigned r = v.u + 0x7FFFu + ((v.u >> 16) & 1u);   // RNE
  return (unsigned short)(r >> 16);
}

__device__ __forceinline__ float bf2f(unsigned short u) {
  union { unsigned u; float f; } v; v.u = ((unsigned)u) << 16; return v.f;
}

__device__ __forceinline__ void pack4(unsigned short* dst, float a, float b, float c, float d) {
  unsigned lo = (unsigned)f2bf(a) | ((unsigned)f2bf(b) << 16);
  unsigned hi = (unsigned)f2bf(c) | ((unsigned)f2bf(d) << 16);
  *reinterpret_cast<uint2*>(dst) = make_uint2(lo, hi);
}

// ---------------- conversion / packing kernels ----------------

__global__ void cvt_bf16_kernel(const float* __restrict__ in, unsigned short* __restrict__ out, int n4) {
  int g = blockIdx.x * blockDim.x + threadIdx.x;
  if (g >= n4) return;
  int base = g * 4;
  float4 v = *reinterpret_cast<const float4*>(in + base);
  pack4(out + base, v.x, v.y, v.z, v.w);
}

// w1p fragment-order: elem ((z*128 + c)*512 + j)*8 + e  =  W1[z][j][c*8+e]
// where W1[z][j][k] = k<512 ? Wl5[z][j][k] : Wr5[z][j][k-512]
__global__ void pack_w1p_kernel(const float* __restrict__ Wl, const float* __restrict__ Wr,
                                unsigned short* __restrict__ out) {
  int g = blockIdx.x * blockDim.x + threadIdx.x;
  if (g >= 5 * 128 * 512) return;
  int z = g >> 16;              // /65536
  int rem = g & 65535;
  int c = rem >> 9;             // 0..127
  int j = rem & 511;
  int kk = c * 8;
  const float* src = (kk < 512) ? (Wl + ((size_t)(z * 512 + j)) * 512 + kk)
                                : (Wr + ((size_t)(z * 512 + j)) * 512 + (kk - 512));
  float4 a = *reinterpret_cast<const float4*>(src);
  float4 b = *reinterpret_cast<const float4*>(src + 4);
  pack4(out + (size_t)g * 8, a.x, a.y, a.z, a.w);
  pack4(out + (size_t)g * 8 + 4, b.x, b.y, b.z, b.w);
}

// w23p fragment-order: elem (c*1024 + j)*8 + e = W23[j][c*8+e]
// W23 rows: [Wmu_l(256); Wlv_l(256); Wmu_r(256); Wlv_r(256)], K=2560
__global__ void pack_w23p_kernel(const float* __restrict__ Wmu_l, const float* __restrict__ Wlv_l,
                                 const float* __restrict__ Wmu_r, const float* __restrict__ Wlv_r,
                                 unsigned short* __restrict__ out) {
  int g = blockIdx.x * blockDim.x + threadIdx.x;
  if (g >= 320 * 1024) return;
  int c = g >> 10;              // 0..319
  int j = g & 1023;
  const float* row;
  if (j < 256)       row = Wmu_l + (size_t)j * CATW;
  else if (j < 512)  row = Wlv_l + (size_t)(j - 256) * CATW;
  else if (j < 768)  row = Wmu_r + (size_t)(j - 512) * CATW;
  else               row = Wlv_r + (size_t)(j - 768) * CATW;
  const float* src = row + c * 8;
  float4 a = *reinterpret_cast<const float4*>(src);
  float4 b = *reinterpret_cast<const float4*>(src + 4);
  pack4(out + (size_t)g * 8, a.x, a.y, a.z, a.w);
  pack4(out + (size_t)g * 8 + 4, b.x, b.y, b.z, b.w);
}

// ---------------- CSR build: key = dst*5 + rel ----------------

__global__ void hist_kernel(const int* __restrict__ ei, const int* __restrict__ ea,
                            int* __restrict__ cnt, int E) {
  int e = blockIdx.x * 256 + threadIdx.x;
  if (e >= E) return;
  atomicAdd(&cnt[ei[E + e] * 5 + ea[e]], 1);
}

__global__ void scan1_kernel(const int* __restrict__ in, int* __restrict__ out,
                             int* __restrict__ bsum, int n) {
  __shared__ int lds[256];
  int t = threadIdx.x;
  int base = blockIdx.x * TS + t * 4;
  int4 v = make_int4(0, 0, 0, 0);
  if (base + 3 < n) v = *reinterpret_cast<const int4*>(in + base);
  else {
    if (base < n) v.x = in[base];
    if (base + 1 < n) v.y = in[base + 1];
    if (base + 2 < n) v.z = in[base + 2];
    if (base + 3 < n) v.w = in[base + 3];
  }
  int s = v.x + v.y + v.z + v.w;
  lds[t] = s;
  __syncthreads();
  for (int o = 1; o < 256; o <<= 1) {
    int a = (t >= o) ? lds[t - o] : 0;
    __syncthreads();
    lds[t] += a;
    __syncthreads();
  }
  int excl = lds[t] - s;
  if (t == 255) bsum[blockIdx.x] = lds[255];
  int e0 = excl, e1 = e0 + v.x, e2 = e1 + v.y, e3 = e2 + v.z;
  if (base < n) out[base] = e0;
  if (base + 1 < n) out[base + 1] = e1;
  if (base + 2 < n) out[base + 2] = e2;
  if (base + 3 < n) out[base + 3] = e3;
}

__global__ void scan2_kernel(int* __restrict__ bsum, int nb) {   // nb <= 128
  __shared__ int lds[128];
  int t = threadIdx.x;
  int v = (t < nb) ? bsum[t] : 0;
  lds[t] = v;
  __syncthreads();
  for (int o = 1; o < 128; o <<= 1) {
    int a = (t >= o) ? lds[t - o] : 0;
    __syncthreads();
    lds[t] += a;
    __syncthreads();
  }
  if (t < nb) bsum[t] = lds[t] - v;   // exclusive
}

__global__ void scan3_kernel(int* __restrict__ out, const int* __restrict__ bsum,
                             int n, int total) {
  int g = blockIdx.x * 256 + threadIdx.x;
  if (g == 0) out[n] = total;
  int base = g * 4;
  if (base >= n) return;
  int add = bsum[base / TS];
  if (base + 3 < n) {
    int4 v = *reinterpret_cast<int4*>(out + base);
    v.x += add; v.y += add; v.z += add; v.w += add;
    *reinterpret_cast<int4*>(out + base) = v;
  } else {
    for (int q = 0; q < 4 && base + q < n; ++q) out[base + q] += add;
  }
}

__global__ void fill_kernel(const int* __restrict__ ei, const int* __restrict__ ea,
                            const int* __restrict__ offs, int* __restrict__ fillc,
                            int* __restrict__ perm, int E) {
  int e = blockIdx.x * 256 + threadIdx.x;
  if (e >= E) return;
  int key = ei[E + e] * 5 + ea[e];
  int p = atomicAdd(&fillc[key], 1);
  perm[offs[key] + p] = ei[e];   // store src
}

// ---------------- gather kernels (no atomics) ----------------

__global__ void gather1_kernel(const unsigned short* __restrict__ xb, const int* __restrict__ offs,
                               const int* __restrict__ perm, unsigned short* __restrict__ meanb5) {
  int i = blockIdx.x;
  int k = blockIdx.y;
  int t = threadIdx.x;
  int b0 = offs[i * 5 + k], b1 = offs[i * 5 + k + 1];
  float a0 = 0.f, a1 = 0.f, a2 = 0.f, a3 = 0.f;
  for (int e = b0; e < b1; ++e) {
    int s = perm[e];
    ushort4 v = reinterpret_cast<const ushort4*>(xb + (size_t)s * 512)[t];
    a0 += bf2f(v.x); a1 += bf2f(v.y); a2 += bf2f(v.z); a3 += bf2f(v.w);
  }
  float inv = (b1 > b0) ? 1.0f / (float)(b1 - b0) : 0.0f;
  pack4(meanb5 + (size_t)i * CATW + k * 512 + t * 4, a0 * inv, a1 * inv, a2 * inv, a3 * inv);
}

// fused: d_out += segment-mean(z) + bias   (mu cols 0..255, logvar cols 256..511)
__global__ void gather2_kernel(const float* __restrict__ z, const int* __restrict__ offs,
                               const int* __restrict__ perm, float* __restrict__ dout,
                               const float* __restrict__ bmu, const float* __restrict__ blv,
                               int M) {
  int i = blockIdx.x;
  int t = threadIdx.x;
  int b0 = offs[i * 5], b1 = offs[i * 5 + 5];
  float4 acc = make_float4(0.f, 0.f, 0.f, 0.f);
  for (int e = b0; e < b1; ++e) {
    int s = perm[e];
    float4 v = reinterpret_cast<const float4*>(z + (size_t)s * 512)[t];
    acc.x += v.x; acc.y += v.y; acc.z += v.z; acc.w += v.w;
  }
  float inv = (b1 > b0) ? 1.0f / (float)(b1 - b0) : 1.0f;
  int c = t * 4;
  float* op;
  const float* bp;
  if (c < 256) { op = dout + (size_t)i * OUTW + c; bp = bmu + c; }
  else         { op = dout + (size_t)M * OUTW + (size_t)i * OUTW + (c - 256); bp = blv + (c - 256); }
  float4 y = *reinterpret_cast<float4*>(op);
  float4 b = *reinterpret_cast<const float4*>(bp);
  y.x += acc.x * inv + b.x; y.y += acc.y * inv + b.y;
  y.z += acc.z * inv + b.z; y.w += acc.w * inv + b.w;
  *reinterpret_cast<float4*>(op) = y;
}

// ---------------- MFMA GEMM: r14 core (128x128, BK=32, 4 waves, A 4-slot LDS ring,
// B direct global->reg ping-pong, raw s_barrier) + LDS-staged coalesced epilogue ----------
// K-loop identical to r14 (verified correct + deterministic). Epilogue change only:
// stage C-tile through the (idle after loop) As buffer and write full 256B row-segments
// per 16-lane group -> no partial-line write amplification (measured 197MB vs ideal 102/82).
// MODE 0: z=blockIdx.z; A=[meanb5 z-chunk | xb] (K=1024), B=w1p[z]; bias->ReLU->BN -> hb
// MODE 1: A=hb (K=2560), B=w23p; j<512 -> zbuf f32; j>=512 -> d_out raw
template<int MODE>
__global__ __launch_bounds__(256, 3)
void gemm_kernel(const unsigned short* __restrict__ A,
                 const unsigned short* __restrict__ A2,
                 const unsigned short* __restrict__ B,
                 unsigned short* __restrict__ hOut,
                 float* __restrict__ fOut,
                 float* __restrict__ fOut2,
                 const float* __restrict__ p0,   // MODE0: bl5
                 const float* __restrict__ p1,   // MODE0: rmean
                 const float* __restrict__ p2,   // MODE0: rvar
                 const float* __restrict__ p3,   // MODE0: gamma
                 const float* __restrict__ p4,   // MODE0: beta
                 int M)
{
  constexpr int KTOT = (MODE == 0) ? (2 * INCH) : CATW;
  constexpr int KT = KTOT / 32;              // 32 / 80 (even)
  constexpr int NBLK = (MODE == 0) ? 4 : 8;  // output cols / 128
  constexpr int NC = (MODE == 0) ? 512 : 1024;   // B col count (fragment-order)

  // bijective XCD-chunked swizzle (m204), col-fastest within an XCD chunk
  const int nwg = gridDim.x;
  const int o = blockIdx.x;
  const int q = nwg >> 3, r = nwg & 7;
  const int xcd = o & 7;
  const int wg = (xcd < r ? xcd * (q + 1) : r * (q + 1) + (xcd - r) * q) + (o >> 3);
  const int rowBase = (wg / NBLK) * 128;
  const int nBase = (wg % NBLK) * 128;
  const int z = (MODE == 0) ? blockIdx.z : 0;
  const unsigned short* BpF = (MODE == 0) ? (B + (size_t)z * 524288) : B;  // z*128*512*8

  __shared__ unsigned short As[4][4096];   // 4-slot ring x [128 rows][32 k] bf16, 32KB

  const int tid = threadIdx.x;
  const int lane = tid & 63;
  const int wv = tid >> 6;                 // 0..3
  const int wr = wv >> 1, wc = wv & 1;
  const int lr = lane & 15, kg = lane >> 4;

  // ---- A staging (r10 geometry): wave wv stages chunks {2wv,2wv+1},
  // chunk = 16 rows x 32 k = 1KB; lane l -> row chunk*16+(l>>2), k-chunk (l&3)^((l>>4)&3).
  const int srow0 = (wv * 2) * 16 + (lane >> 2);
  const int srow1 = srow0 + 16;
  const int kswz = (((lane & 3) ^ ((lane >> 4) & 3)) * 8);   // elements
  int gar0 = rowBase + srow0; if (gar0 >= M) gar0 = M - 1;
  int gar1 = rowBase + srow1; if (gar1 >= M) gar1 = M - 1;

  // ---- A fragment read slots: ar*32 + ((kg ^ ((lr>>2)&3))*8)  (involution pair w/ kswz)
  int aslot[4];
#pragma unroll
  for (int m = 0; m < 4; ++m) {
    const int ar = wr * 64 + m * 16 + lr;
    aslot[m] = ar * 32 + ((kg ^ ((lr >> 2) & 3)) * 8);
  }

  // ---- B fragment-order offsets: elem ((c*NC) + j)*8, c = kt*4+kg, j = col row
  size_t bjoff[4];
#pragma unroll
  for (int n = 0; n < 4; ++n)
    bjoff[n] = (size_t)(nBase + wc * 64 + n * 16 + lr) * 8;

  f32x4 acc[4][4] = {};

  auto stageA = [&](int slot, int kt) {
    const int kk0 = kt * 32;
    const unsigned short *a0p, *a1p;
    if (MODE == 0) {
      if (kk0 < INCH) {
        a0p = A + (size_t)gar0 * CATW + z * 512 + kk0 + kswz;
        a1p = A + (size_t)gar1 * CATW + z * 512 + kk0 + kswz;
      } else {
        a0p = A2 + (size_t)gar0 * INCH + (kk0 - INCH) + kswz;
        a1p = A2 + (size_t)gar1 * INCH + (kk0 - INCH) + kswz;
      }
    } else {
      a0p = A + (size_t)gar0 * KTOT + kk0 + kswz;
      a1p = A + (size_t)gar1 * KTOT + kk0 + kswz;
    }
    __builtin_amdgcn_global_load_lds((const void*)a0p, (void*)&As[slot][(wv * 2) * 512], 16, 0, 0);
    __builtin_amdgcn_global_load_lds((const void*)a1p, (void*)&As[slot][(wv * 2 + 1) * 512], 16, 0, 0);
  };

  auto loadB = [&](int kt, bf16x8 (&dst)[4]) {
    const size_t cbase = (size_t)((kt << 2) + kg) * NC * 8;
#pragma unroll
    for (int n = 0; n < 4; ++n)
      dst[n] = *reinterpret_cast<const bf16x8*>(BpF + cbase + bjoff[n]);
  };

  // one step: ds_read A(t) | loadB(t+1) | stageA(t+3) | MFMA(t) | raw s_barrier
  auto step = [&](int t, const bf16x8 (&bcur)[4], bf16x8 (&bnxt)[4]) {
    const int slot = t & 3;
    bf16x8 af[4];
#pragma unroll
    for (int m = 0; m < 4; ++m)
      af[m] = *reinterpret_cast<const bf16x8*>(&As[slot][aslot[m]]);
    if (t + 1 < KT) loadB(t + 1, bnxt);           // B first (older than stage(t+3))
    if (t + 3 < KT) stageA((t + 3) & 3, t + 3);   // 3-deep A prefetch
    __builtin_amdgcn_sched_barrier(0);
    __builtin_amdgcn_s_setprio(1);
#pragma unroll
    for (int m = 0; m < 4; ++m)
#pragma unroll
      for (int n = 0; n < 4; ++n)
        acc[m][n] = __builtin_amdgcn_mfma_f32_16x16x32_bf16(af[m], bcur[n], acc[m][n], 0, 0, 0);
    __builtin_amdgcn_s_setprio(0);
    __builtin_amdgcn_sched_barrier(0);
    __builtin_amdgcn_s_barrier();       // raw barrier: NO vmcnt drain
    __builtin_amdgcn_sched_barrier(0);
  };

  // ---- prologue: A(0..2) staged; B(0) in regs; wait A(0) only
  bf16x8 bP[4], bQ[4];
  stageA(0, 0);
  stageA(1, 1);
  stageA(2, 2);
  __builtin_amdgcn_sched_barrier(0);
  loadB(0, bP);
  __builtin_amdgcn_sched_barrier(0);
  asm volatile("s_waitcnt vmcnt(8)" ::: "memory");   // A(0) landed; A(1),A(2),B(0) in flight
  __builtin_amdgcn_s_barrier();
  __builtin_amdgcn_sched_barrier(0);

  for (int t = 0; t < KT; t += 2) {   // KT even
    step(t, bP, bQ);
    step(t + 1, bQ, bP);
  }

  // ---- epilogue: LDS-staged coalesced writes (loop's trailing s_barrier separates
  // the K-loop's LDS reads from these writes; As is idle now)
  if (MODE == 0) {
    unsigned short* lds16 = &As[0][0];   // 128x128 bf16 tile, col-XOR swizzled
#pragma unroll
    for (int n = 0; n < 4; ++n) {
      const int j = wc * 64 + n * 16 + lr;           // local col
      const int ch = z * 512 + nBase + j;
      const float bias = p0[ch];
      const float scale = rsqrtf(p2[ch] + BN_EPS) * p3[ch];
      const float rm = p1[ch], be = p4[ch];
#pragma unroll
      for (int m = 0; m < 4; ++m)
#pragma unroll
        for (int rr = 0; rr < 4; ++rr) {
          const int row = wr * 64 + m * 16 + kg * 4 + rr;   // local row
          float v = acc[m][n][rr] + bias;   // SAGE output
          v = fmaxf(v, 0.0f);               // ReLU FIRST (reference order)
          v = (v - rm) * scale + be;        // BN SECOND
          lds16[row * 128 + (j ^ ((row & 7) << 3))] = f2bf(v);
        }
    }
    __syncthreads();
    const int trow = tid >> 4;          // 0..15
    const int cb = tid & 15;            // 16B (8-bf16) col block
#pragma unroll
    for (int p = 0; p < 8; ++p) {
      const int row = p * 16 + trow;
      const int i = rowBase + row;
      if (i < M) {
        const int scb = cb ^ (row & 7);   // stored pos scb holds original block scb^(row&7)=cb
        uint4 v = *reinterpret_cast<const uint4*>(&lds16[row * 128 + scb * 8]);
        *reinterpret_cast<uint4*>(&hOut[(size_t)i * CATW + z * 512 + nBase + cb * 8]) = v;
      }
    }
  } else {
    float* ldsf = reinterpret_cast<float*>(&As[0][0]);   // 128x64 f32 half-tile (32KB)
#pragma unroll
    for (int hp = 0; hp < 2; ++hp) {
      __syncthreads();
      if (wc == hp) {                    // waves wc==hp own cols [hp*64, hp*64+64)
#pragma unroll
        for (int n = 0; n < 4; ++n) {
          const int jl = n * 16 + lr;    // 0..63 within half
#pragma unroll
          for (int m = 0; m < 4; ++m)
#pragma unroll
            for (int rr = 0; rr < 4; ++rr) {
              const int row = wr * 64 + m * 16 + kg * 4 + rr;
              ldsf[row * 64 + jl] = acc[m][n][rr];
            }
        }
      }
      __syncthreads();
      const int trow = tid >> 4, cb = tid & 15;
      const int jbase = nBase + hp * 64;           // global col base of this half
#pragma unroll
      for (int p = 0; p < 8; ++p) {
        const int row = p * 16 + trow;
        const int i = rowBase + row;
        if (i < M) {
          float4 v = *reinterpret_cast<const float4*>(&ldsf[row * 64 + cb * 4]);
          const int j = jbase + cb * 4;
          float* dst;
          if (j < 512) {
            dst = fOut + (size_t)i * 512 + j;                       // zbuf
          } else {
            const int jj = j - 512;
            dst = (jj < OUTW) ? (fOut2 + (size_t)i * OUTW + jj)     // y3 mu (raw)
                              : (fOut2 + (size_t)M * OUTW + (size_t)i * OUTW + (jj - OUTW));
          }
          *reinterpret_cast<float4*>(dst) = v;
        }
      }
    }
  }
}

// ---------------- launch ----------------

extern "C" void kernel_launch(void* const* d_in, const int* in_sizes, int n_in,
                              void* d_out, int out_size, void* d_ws, size_t ws_size,
                              hipStream_t stream) {
  const float* x     = (const float*)d_in[0];
  const int*   ei    = (const int*)d_in[1];
  const int*   ea    = (const int*)d_in[2];
  const float* Wl5   = (const float*)d_in[3];
  const float* Wr5   = (const float*)d_in[4];
  const float* bl5   = (const float*)d_in[5];
  const float* Wmu_l = (const float*)d_in[6];
  const float* Wmu_r = (const float*)d_in[7];
  const float* bmu   = (const float*)d_in[8];
  const float* Wlv_l = (const float*)d_in[9];
  const float* Wlv_r = (const float*)d_in[10];
  const float* blv   = (const float*)d_in[11];
  const float* gamma = (const float*)d_in[12];
  const float* beta  = (const float*)d_in[13];
  const float* rmean = (const float*)d_in[14];
  const float* rvar  = (const float*)d_in[15];
  (void)n_in; (void)out_size;

  const int N = in_sizes[0] / INCH;   // 20000
  const int E = in_sizes[2];          // 100000
  const int NKEY = N * 5;

  // ---- workspace layout (~202 MB) ----
  char* ws = (char*)d_ws;
  size_t off = 0;
  auto take = [&](size_t bytes) { char* p = ws + off; off += (bytes + 255) & ~(size_t)255; return p; };
  unsigned short* hb = (unsigned short*)take((size_t)N * CATW * 2);      // 102.4 MB
  char* U = take((size_t)N * CATW * 2);                                  // 102.4 MB: meanb5, later zbuf
  unsigned short* xb = (unsigned short*)take((size_t)N * 512 * 2);       // 20.5 MB
  unsigned short* w1p  = (unsigned short*)take((size_t)5 * 128 * 512 * 8 * 2);  // 5.24 MB
  unsigned short* w23p = (unsigned short*)take((size_t)320 * 1024 * 8 * 2);     // 5.24 MB
  int* cntk  = (int*)take((size_t)NKEY * 4);
  int* offs  = (int*)take((size_t)(NKEY + 1) * 4);
  int* fillc = (int*)take((size_t)NKEY * 4);
  int* perm  = (int*)take((size_t)E * 4);
  int* bsum  = (int*)take(256 * 4);
  if (off > ws_size) return;  // diagnostic guard -> clean absmax-488 failure

  unsigned short* meanb5 = (unsigned short*)U;         // [N,5,512] bf16 (layer-1 life)
  float* zbuf  = (float*)U;                            // [N,512] f32 (layer-2 life)

  // conversions / packing (fragment-order weights)
  cvt_bf16_kernel<<<dim3((N * INCH / 4 + 255) / 256), 256, 0, stream>>>(x, xb, N * INCH / 4);
  pack_w1p_kernel<<<dim3((5 * 128 * 512 + 255) / 256), 256, 0, stream>>>(Wl5, Wr5, w1p);
  pack_w23p_kernel<<<dim3((320 * 1024 + 255) / 256), 256, 0, stream>>>(Wmu_l, Wlv_l, Wmu_r, Wlv_r, w23p);

  // CSR build: key = dst*5 + rel
  hipMemsetAsync(cntk, 0, (size_t)NKEY * 4, stream);
  hipMemsetAsync(fillc, 0, (size_t)NKEY * 4, stream);
  hist_kernel<<<dim3((E + 255) / 256), 256, 0, stream>>>(ei, ea, cntk, E);
  const int nb = (NKEY + TS - 1) / TS;
  scan1_kernel<<<dim3(nb), 256, 0, stream>>>(cntk, offs, bsum, NKEY);
  scan2_kernel<<<dim3(1), 128, 0, stream>>>(bsum, nb);
  scan3_kernel<<<dim3((NKEY / 4 + 255) / 256 + 1), 256, 0, stream>>>(offs, bsum, NKEY, E);
  fill_kernel<<<dim3((E + 255) / 256), 256, 0, stream>>>(ei, ea, offs, fillc, perm, E);

  // layer 1: all 5 relation means, then ONE batched GEMM dispatch (z = relation)
  gather1_kernel<<<dim3(N, 5), 128, 0, stream>>>(xb, offs, perm, meanb5);
  const int mblk = (N + 127) / 128;    // 157 row-tiles of 128
  gemm_kernel<0><<<dim3(mblk * 4, 1, 5), 256, 0, stream>>>(
      meanb5, xb, w1p, hb, nullptr, nullptr,
      bl5, rmean, rvar, gamma, beta, N);

  // layer 2: one pass over hb computes z (->zbuf) and y3 (->d_out)
  gemm_kernel<1><<<dim3(mblk * 8, 1, 1), 256, 0, stream>>>(
      hb, nullptr, w23p, nullptr, zbuf, (float*)d_out,
      nullptr, nullptr, nullptr, nullptr, nullptr, N);

  // fused: d_out += segment-mean(zbuf) + bias
  gather2_kernel<<<dim3(N), 128, 0, stream>>>(zbuf, offs, perm, (float*)d_out, bmu, blv, N);
}

// Round 16
// 351.712 us; speedup vs baseline: 1.2723x; 1.0489x over previous
//
#include <hip/hip_runtime.h>
#include <stdint.h>

#define INCH 512
#define HIDW 512
#define CATW 2560
#define OUTW 256
#define BN_EPS 1e-5f
#define TS 1024   // scan tile

typedef __bf16 bf16x8 __attribute__((ext_vector_type(8)));
typedef float f32x4 __attribute__((ext_vector_type(4)));

__device__ __forceinline__ unsigned short f2bf(float f) {
  union { float f; unsigned u; } v; v.f = f;
  unsigned r = v.u + 0x7FFFu + ((v.u >> 16) & 1u);   // RNE
  return (unsigned short)(r >> 16);
}

__device__ __forceinline__ float bf2f(unsigned short u) {
  union { unsigned u; float f; } v; v.u = ((unsigned)u) << 16; return v.f;
}

__device__ __forceinline__ void pack4(unsigned short* dst, float a, float b, float c, float d) {
  unsigned lo = (unsigned)f2bf(a) | ((unsigned)f2bf(b) << 16);
  unsigned hi = (unsigned)f2bf(c) | ((unsigned)f2bf(d) << 16);
  *reinterpret_cast<uint2*>(dst) = make_uint2(lo, hi);
}

// ---------------- conversion / packing kernels ----------------

__global__ void cvt_bf16_kernel(const float* __restrict__ in, unsigned short* __restrict__ out, int n4) {
  int g = blockIdx.x * blockDim.x + threadIdx.x;
  if (g >= n4) return;
  int base = g * 4;
  float4 v = *reinterpret_cast<const float4*>(in + base);
  pack4(out + base, v.x, v.y, v.z, v.w);
}

// w1p fragment-order: elem ((z*128 + c)*512 + j)*8 + e  =  W1[z][j][c*8+e]
__global__ void pack_w1p_kernel(const float* __restrict__ Wl, const float* __restrict__ Wr,
                                unsigned short* __restrict__ out) {
  int g = blockIdx.x * blockDim.x + threadIdx.x;
  if (g >= 5 * 128 * 512) return;
  int z = g >> 16;
  int rem = g & 65535;
  int c = rem >> 9;             // 0..127
  int j = rem & 511;
  int kk = c * 8;
  const float* src = (kk < 512) ? (Wl + ((size_t)(z * 512 + j)) * 512 + kk)
                                : (Wr + ((size_t)(z * 512 + j)) * 512 + (kk - 512));
  float4 a = *reinterpret_cast<const float4*>(src);
  float4 b = *reinterpret_cast<const float4*>(src + 4);
  pack4(out + (size_t)g * 8, a.x, a.y, a.z, a.w);
  pack4(out + (size_t)g * 8 + 4, b.x, b.y, b.z, b.w);
}

// w23p fragment-order: elem (c*1024 + j)*8 + e = W23[j][c*8+e]
__global__ void pack_w23p_kernel(const float* __restrict__ Wmu_l, const float* __restrict__ Wlv_l,
                                 const float* __restrict__ Wmu_r, const float* __restrict__ Wlv_r,
                                 unsigned short* __restrict__ out) {
  int g = blockIdx.x * blockDim.x + threadIdx.x;
  if (g >= 320 * 1024) return;
  int c = g >> 10;              // 0..319
  int j = g & 1023;
  const float* row;
  if (j < 256)       row = Wmu_l + (size_t)j * CATW;
  else if (j < 512)  row = Wlv_l + (size_t)(j - 256) * CATW;
  else if (j < 768)  row = Wmu_r + (size_t)(j - 512) * CATW;
  else               row = Wlv_r + (size_t)(j - 768) * CATW;
  const float* src = row + c * 8;
  float4 a = *reinterpret_cast<const float4*>(src);
  float4 b = *reinterpret_cast<const float4*>(src + 4);
  pack4(out + (size_t)g * 8, a.x, a.y, a.z, a.w);
  pack4(out + (size_t)g * 8 + 4, b.x, b.y, b.z, b.w);
}

// ---------------- CSR build: key = dst*5 + rel ----------------

__global__ void hist_kernel(const int* __restrict__ ei, const int* __restrict__ ea,
                            int* __restrict__ cnt, int E) {
  int e = blockIdx.x * 256 + threadIdx.x;
  if (e >= E) return;
  atomicAdd(&cnt[ei[E + e] * 5 + ea[e]], 1);
}

__global__ void scan1_kernel(const int* __restrict__ in, int* __restrict__ out,
                             int* __restrict__ bsum, int n) {
  __shared__ int lds[256];
  int t = threadIdx.x;
  int base = blockIdx.x * TS + t * 4;
  int4 v = make_int4(0, 0, 0, 0);
  if (base + 3 < n) v = *reinterpret_cast<const int4*>(in + base);
  else {
    if (base < n) v.x = in[base];
    if (base + 1 < n) v.y = in[base + 1];
    if (base + 2 < n) v.z = in[base + 2];
    if (base + 3 < n) v.w = in[base + 3];
  }
  int s = v.x + v.y + v.z + v.w;
  lds[t] = s;
  __syncthreads();
  for (int o = 1; o < 256; o <<= 1) {
    int a = (t >= o) ? lds[t - o] : 0;
    __syncthreads();
    lds[t] += a;
    __syncthreads();
  }
  int excl = lds[t] - s;
  if (t == 255) bsum[blockIdx.x] = lds[255];
  int e0 = excl, e1 = e0 + v.x, e2 = e1 + v.y, e3 = e2 + v.z;
  if (base < n) out[base] = e0;
  if (base + 1 < n) out[base + 1] = e1;
  if (base + 2 < n) out[base + 2] = e2;
  if (base + 3 < n) out[base + 3] = e3;
}

__global__ void scan2_kernel(int* __restrict__ bsum, int nb) {   // nb <= 128
  __shared__ int lds[128];
  int t = threadIdx.x;
  int v = (t < nb) ? bsum[t] : 0;
  lds[t] = v;
  __syncthreads();
  for (int o = 1; o < 128; o <<= 1) {
    int a = (t >= o) ? lds[t - o] : 0;
    __syncthreads();
    lds[t] += a;
    __syncthreads();
  }
  if (t < nb) bsum[t] = lds[t] - v;   // exclusive
}

__global__ void scan3_kernel(int* __restrict__ out, const int* __restrict__ bsum,
                             int n, int total) {
  int g = blockIdx.x * 256 + threadIdx.x;
  if (g == 0) out[n] = total;
  int base = g * 4;
  if (base >= n) return;
  int add = bsum[base / TS];
  if (base + 3 < n) {
    int4 v = *reinterpret_cast<int4*>(out + base);
    v.x += add; v.y += add; v.z += add; v.w += add;
    *reinterpret_cast<int4*>(out + base) = v;
  } else {
    for (int q = 0; q < 4 && base + q < n; ++q) out[base + q] += add;
  }
}

__global__ void fill_kernel(const int* __restrict__ ei, const int* __restrict__ ea,
                            const int* __restrict__ offs, int* __restrict__ fillc,
                            int* __restrict__ perm, int E) {
  int e = blockIdx.x * 256 + threadIdx.x;
  if (e >= E) return;
  int key = ei[E + e] * 5 + ea[e];
  int p = atomicAdd(&fillc[key], 1);
  perm[offs[key] + p] = ei[e];   // store src
}

// ---------------- gather kernels (no atomics) ----------------

// one block per node: all 5 relation means, 5KB contiguous write
__global__ void gather1_kernel(const unsigned short* __restrict__ xb, const int* __restrict__ offs,
                               const int* __restrict__ perm, unsigned short* __restrict__ meanb5) {
  int i = blockIdx.x;
  int t = threadIdx.x;
#pragma unroll
  for (int k = 0; k < 5; ++k) {
    int b0 = offs[i * 5 + k], b1 = offs[i * 5 + k + 1];
    float a0 = 0.f, a1 = 0.f, a2 = 0.f, a3 = 0.f;
    for (int e = b0; e < b1; ++e) {
      int s = perm[e];
      ushort4 v = reinterpret_cast<const ushort4*>(xb + (size_t)s * 512)[t];
      a0 += bf2f(v.x); a1 += bf2f(v.y); a2 += bf2f(v.z); a3 += bf2f(v.w);
    }
    float inv = (b1 > b0) ? 1.0f / (float)(b1 - b0) : 0.0f;
    pack4(meanb5 + (size_t)i * CATW + k * 512 + t * 4, a0 * inv, a1 * inv, a2 * inv, a3 * inv);
  }
}

// fused: d_out += segment-mean(z, bf16) + bias   (mu cols 0..255, logvar cols 256..511)
__global__ void gather2_kernel(const unsigned short* __restrict__ zb, const int* __restrict__ offs,
                               const int* __restrict__ perm, float* __restrict__ dout,
                               const float* __restrict__ bmu, const float* __restrict__ blv,
                               int M) {
  int i = blockIdx.x;
  int t = threadIdx.x;
  int b0 = offs[i * 5], b1 = offs[i * 5 + 5];
  float a0 = 0.f, a1 = 0.f, a2 = 0.f, a3 = 0.f;
  for (int e = b0; e < b1; ++e) {
    int s = perm[e];
    ushort4 v = reinterpret_cast<const ushort4*>(zb + (size_t)s * 512)[t];
    a0 += bf2f(v.x); a1 += bf2f(v.y); a2 += bf2f(v.z); a3 += bf2f(v.w);
  }
  float inv = (b1 > b0) ? 1.0f / (float)(b1 - b0) : 1.0f;
  int c = t * 4;
  float* op;
  const float* bp;
  if (c < 256) { op = dout + (size_t)i * OUTW + c; bp = bmu + c; }
  else         { op = dout + (size_t)M * OUTW + (size_t)i * OUTW + (c - 256); bp = blv + (c - 256); }
  float4 y = *reinterpret_cast<float4*>(op);
  float4 b = *reinterpret_cast<const float4*>(bp);
  y.x += a0 * inv + b.x; y.y += a1 * inv + b.y;
  y.z += a2 * inv + b.z; y.w += a3 * inv + b.w;
  *reinterpret_cast<float4*>(op) = y;
}

// ---------------- MFMA GEMM: r14 core + 2-tile superstep (half the barriers) +
// r15 LDS-staged coalesced epilogue ----------------
// 6-slot A ring, B reg ping-pong. Steady-state invariant (per-wave VM queue): the
// compiler's pre-MFMA(t+1) wait for bQ=B(t+1) has static count vmcnt(8) (newer:
// stage(t+4), B(t+2), stage(t+5)), retiring stage(t+2),stage(t+3) before the trailing
// barrier -> tiles t+2,t+3 provably landed for the next superstep; NO explicit mid-loop
// waits. Tail 2 supersteps (guarded loads) drain with vmcnt(0) before their barriers.
// MODE 0: z=blockIdx.z; A=[meanb5 z-chunk | xb] (K=1024), B=w1p[z]; bias->ReLU->BN -> hb
// MODE 1: A=hb (K=2560), B=w23p; j<512 -> zb (bf16); j>=512 -> d_out raw
template<int MODE>
__global__ __launch_bounds__(256, 3)
void gemm_kernel(const unsigned short* __restrict__ A,
                 const unsigned short* __restrict__ A2,
                 const unsigned short* __restrict__ B,
                 unsigned short* __restrict__ hOut,
                 unsigned short* __restrict__ zbOut,
                 float* __restrict__ fOut2,
                 const float* __restrict__ p0,   // MODE0: bl5
                 const float* __restrict__ p1,   // MODE0: rmean
                 const float* __restrict__ p2,   // MODE0: rvar
                 const float* __restrict__ p3,   // MODE0: gamma
                 const float* __restrict__ p4,   // MODE0: beta
                 int M)
{
  constexpr int KTOT = (MODE == 0) ? (2 * INCH) : CATW;
  constexpr int KT = KTOT / 32;              // 32 / 80 (divisible by 4)
  constexpr int NBLK = (MODE == 0) ? 4 : 8;  // output cols / 128
  constexpr int NC = (MODE == 0) ? 512 : 1024;   // B col count (fragment-order)

  // bijective XCD-chunked swizzle (m204), col-fastest within an XCD chunk
  const int nwg = gridDim.x;
  const int o = blockIdx.x;
  const int q = nwg >> 3, r = nwg & 7;
  const int xcd = o & 7;
  const int wg = (xcd < r ? xcd * (q + 1) : r * (q + 1) + (xcd - r) * q) + (o >> 3);
  const int rowBase = (wg / NBLK) * 128;
  const int nBase = (wg % NBLK) * 128;
  const int z = (MODE == 0) ? blockIdx.z : 0;
  const unsigned short* BpF = (MODE == 0) ? (B + (size_t)z * 524288) : B;  // z*128*512*8

  __shared__ unsigned short As[6][4096];   // 6-slot ring x [128 rows][32 k] bf16, 48KB

  const int tid = threadIdx.x;
  const int lane = tid & 63;
  const int wv = tid >> 6;                 // 0..3
  const int wr = wv >> 1, wc = wv & 1;
  const int lr = lane & 15, kg = lane >> 4;

  // A staging (r10 geometry): wave wv stages chunks {2wv,2wv+1},
  // chunk = 16 rows x 32 k = 1KB; lane l -> row chunk*16+(l>>2), k-chunk (l&3)^((l>>4)&3).
  const int srow0 = (wv * 2) * 16 + (lane >> 2);
  const int srow1 = srow0 + 16;
  const int kswz = (((lane & 3) ^ ((lane >> 4) & 3)) * 8);   // elements
  int gar0 = rowBase + srow0; if (gar0 >= M) gar0 = M - 1;
  int gar1 = rowBase + srow1; if (gar1 >= M) gar1 = M - 1;

  // A fragment read slots: ar*32 + ((kg ^ ((lr>>2)&3))*8)  (involution pair w/ kswz)
  int aslot[4];
#pragma unroll
  for (int m = 0; m < 4; ++m) {
    const int ar = wr * 64 + m * 16 + lr;
    aslot[m] = ar * 32 + ((kg ^ ((lr >> 2) & 3)) * 8);
  }

  // B fragment-order offsets: elem ((c*NC) + j)*8, c = kt*4+kg
  size_t bjoff[4];
#pragma unroll
  for (int n = 0; n < 4; ++n)
    bjoff[n] = (size_t)(nBase + wc * 64 + n * 16 + lr) * 8;

  f32x4 acc[4][4] = {};

  auto stageA = [&](int slot, int kt) {
    const int kk0 = kt * 32;
    const unsigned short *a0p, *a1p;
    if (MODE == 0) {
      if (kk0 < INCH) {
        a0p = A + (size_t)gar0 * CATW + z * 512 + kk0 + kswz;
        a1p = A + (size_t)gar1 * CATW + z * 512 + kk0 + kswz;
      } else {
        a0p = A2 + (size_t)gar0 * INCH + (kk0 - INCH) + kswz;
        a1p = A2 + (size_t)gar1 * INCH + (kk0 - INCH) + kswz;
      }
    } else {
      a0p = A + (size_t)gar0 * KTOT + kk0 + kswz;
      a1p = A + (size_t)gar1 * KTOT + kk0 + kswz;
    }
    __builtin_amdgcn_global_load_lds((const void*)a0p, (void*)&As[slot][(wv * 2) * 512], 16, 0, 0);
    __builtin_amdgcn_global_load_lds((const void*)a1p, (void*)&As[slot][(wv * 2 + 1) * 512], 16, 0, 0);
  };

  auto loadB = [&](int kt, bf16x8 (&dst)[4]) {
    const size_t cbase = (size_t)((kt << 2) + kg) * NC * 8;
#pragma unroll
    for (int n = 0; n < 4; ++n)
      dst[n] = *reinterpret_cast<const bf16x8*>(BpF + cbase + bjoff[n]);
  };

  auto mfma16 = [&](const bf16x8 (&af)[4], const bf16x8 (&b)[4]) {
    __builtin_amdgcn_s_setprio(1);
#pragma unroll
    for (int m = 0; m < 4; ++m)
#pragma unroll
      for (int n = 0; n < 4; ++n)
        acc[m][n] = __builtin_amdgcn_mfma_f32_16x16x32_bf16(af[m], b[n], acc[m][n], 0, 0, 0);
    __builtin_amdgcn_s_setprio(0);
  };

  // 2-tile superstep (t even): one barrier per 2 K-tiles
  auto superstep = [&](int t, bf16x8 (&bP)[4], bf16x8 (&bQ)[4], bool tail) {
    // half 1: tile t (uses bP)
    {
      const int slot = t % 6;
      bf16x8 af[4];
#pragma unroll
      for (int m = 0; m < 4; ++m)
        af[m] = *reinterpret_cast<const bf16x8*>(&As[slot][aslot[m]]);
      loadB(t + 1, bQ);                              // B older than stage(t+4)
      if (t + 4 < KT) stageA((t + 4) % 6, t + 4);
      __builtin_amdgcn_sched_barrier(0);
      mfma16(af, bP);
      __builtin_amdgcn_sched_barrier(0);
    }
    // half 2: tile t+1 (uses bQ)
    {
      const int slot = (t + 1) % 6;
      bf16x8 af[4];
#pragma unroll
      for (int m = 0; m < 4; ++m)
        af[m] = *reinterpret_cast<const bf16x8*>(&As[slot][aslot[m]]);
      if (t + 2 < KT) loadB(t + 2, bP);
      if (t + 5 < KT) stageA((t + 5) % 6, t + 5);
      __builtin_amdgcn_sched_barrier(0);
      mfma16(af, bQ);
      __builtin_amdgcn_sched_barrier(0);
    }
    if (tail) asm volatile("s_waitcnt vmcnt(0)" ::: "memory");
    __builtin_amdgcn_s_barrier();
    __builtin_amdgcn_sched_barrier(0);
  };

  // ---- prologue: B(0) then tiles 0..3 staged; retire B(0)+s(0)+s(1), keep s(2),s(3)
  bf16x8 bP[4], bQ[4];
  loadB(0, bP);
  stageA(0, 0); stageA(1, 1); stageA(2, 2); stageA(3, 3);
  __builtin_amdgcn_sched_barrier(0);
  asm volatile("s_waitcnt vmcnt(4)" ::: "memory");
  __builtin_amdgcn_s_barrier();
  __builtin_amdgcn_sched_barrier(0);

  // main: full-guard supersteps, then 2 tail supersteps with drain
  int t = 0;
  for (; t < KT - 4; t += 2) superstep(t, bP, bQ, false);
  superstep(t, bP, bQ, true); t += 2;
  superstep(t, bP, bQ, true);

  // ---- epilogue: LDS-staged coalesced writes (r15-verified)
  if (MODE == 0) {
    unsigned short* lds16 = &As[0][0];   // 128x128 bf16 tile, col-XOR swizzled
#pragma unroll
    for (int n = 0; n < 4; ++n) {
      const int j = wc * 64 + n * 16 + lr;           // local col
      const int ch = z * 512 + nBase + j;
      const float bias = p0[ch];
      const float scale = rsqrtf(p2[ch] + BN_EPS) * p3[ch];
      const float rm = p1[ch], be = p4[ch];
#pragma unroll
      for (int m = 0; m < 4; ++m)
#pragma unroll
        for (int rr = 0; rr < 4; ++rr) {
          const int row = wr * 64 + m * 16 + kg * 4 + rr;   // local row
          float v = acc[m][n][rr] + bias;   // SAGE output
          v = fmaxf(v, 0.0f);               // ReLU FIRST (reference order)
          v = (v - rm) * scale + be;        // BN SECOND
          lds16[row * 128 + (j ^ ((row & 7) << 3))] = f2bf(v);
        }
    }
    __syncthreads();
    const int trow = tid >> 4;          // 0..15
    const int cb = tid & 15;            // 16B (8-bf16) col block
#pragma unroll
    for (int p = 0; p < 8; ++p) {
      const int row = p * 16 + trow;
      const int i = rowBase + row;
      if (i < M) {
        const int scb = cb ^ (row & 7);
        uint4 v = *reinterpret_cast<const uint4*>(&lds16[row * 128 + scb * 8]);
        *reinterpret_cast<uint4*>(&hOut[(size_t)i * CATW + z * 512 + nBase + cb * 8]) = v;
      }
    }
  } else {
    float* ldsf = reinterpret_cast<float*>(&As[0][0]);   // 128x64 f32 half-tile (32KB)
#pragma unroll
    for (int hp = 0; hp < 2; ++hp) {
      __syncthreads();
      if (wc == hp) {                    // waves wc==hp own cols [hp*64, hp*64+64)
#pragma unroll
        for (int n = 0; n < 4; ++n) {
          const int jl = n * 16 + lr;    // 0..63 within half
#pragma unroll
          for (int m = 0; m < 4; ++m)
#pragma unroll
            for (int rr = 0; rr < 4; ++rr) {
              const int row = wr * 64 + m * 16 + kg * 4 + rr;
              ldsf[row * 64 + jl] = acc[m][n][rr];
            }
        }
      }
      __syncthreads();
      const int trow = tid >> 4, cb = tid & 15;
      const int jbase = nBase + hp * 64;
#pragma unroll
      for (int p = 0; p < 8; ++p) {
        const int row = p * 16 + trow;
        const int i = rowBase + row;
        if (i < M) {
          float4 v = *reinterpret_cast<const float4*>(&ldsf[row * 64 + cb * 4]);
          const int j = jbase + cb * 4;
          if (j < 512) {
            pack4(zbOut + (size_t)i * 512 + j, v.x, v.y, v.z, v.w);   // zb bf16
          } else {
            const int jj = j - 512;
            float* dst = (jj < OUTW) ? (fOut2 + (size_t)i * OUTW + jj)
                                     : (fOut2 + (size_t)M * OUTW + (size_t)i * OUTW + (jj - OUTW));
            *reinterpret_cast<float4*>(dst) = v;
          }
        }
      }
    }
  }
}

// ---------------- launch ----------------

extern "C" void kernel_launch(void* const* d_in, const int* in_sizes, int n_in,
                              void* d_out, int out_size, void* d_ws, size_t ws_size,
                              hipStream_t stream) {
  const float* x     = (const float*)d_in[0];
  const int*   ei    = (const int*)d_in[1];
  const int*   ea    = (const int*)d_in[2];
  const float* Wl5   = (const float*)d_in[3];
  const float* Wr5   = (const float*)d_in[4];
  const float* bl5   = (const float*)d_in[5];
  const float* Wmu_l = (const float*)d_in[6];
  const float* Wmu_r = (const float*)d_in[7];
  const float* bmu   = (const float*)d_in[8];
  const float* Wlv_l = (const float*)d_in[9];
  const float* Wlv_r = (const float*)d_in[10];
  const float* blv   = (const float*)d_in[11];
  const float* gamma = (const float*)d_in[12];
  const float* beta  = (const float*)d_in[13];
  const float* rmean = (const float*)d_in[14];
  const float* rvar  = (const float*)d_in[15];
  (void)n_in; (void)out_size;

  const int N = in_sizes[0] / INCH;   // 20000
  const int E = in_sizes[2];          // 100000
  const int NKEY = N * 5;

  // ---- workspace layout (~182 MB) ----
  char* ws = (char*)d_ws;
  size_t off = 0;
  auto take = [&](size_t bytes) { char* p = ws + off; off += (bytes + 255) & ~(size_t)255; return p; };
  unsigned short* hb = (unsigned short*)take((size_t)N * CATW * 2);      // 102.4 MB
  char* U = take((size_t)N * CATW * 2);                                  // 102.4 MB: meanb5, later zb
  unsigned short* xb = (unsigned short*)take((size_t)N * 512 * 2);       // 20.5 MB
  unsigned short* w1p  = (unsigned short*)take((size_t)5 * 128 * 512 * 8 * 2);  // 5.24 MB
  unsigned short* w23p = (unsigned short*)take((size_t)320 * 1024 * 8 * 2);     // 5.24 MB
  int* cntk  = (int*)take((size_t)NKEY * 4);
  int* offs  = (int*)take((size_t)(NKEY + 1) * 4);
  int* fillc = (int*)take((size_t)NKEY * 4);
  int* perm  = (int*)take((size_t)E * 4);
  int* bsum  = (int*)take(256 * 4);
  if (off > ws_size) return;  // diagnostic guard -> clean absmax-488 failure

  unsigned short* meanb5 = (unsigned short*)U;         // [N,5,512] bf16 (layer-1 life)
  unsigned short* zb = (unsigned short*)U;             // [N,512] bf16 (layer-2 life)

  // conversions / packing (fragment-order weights)
  cvt_bf16_kernel<<<dim3((N * INCH / 4 + 255) / 256), 256, 0, stream>>>(x, xb, N * INCH / 4);
  pack_w1p_kernel<<<dim3((5 * 128 * 512 + 255) / 256), 256, 0, stream>>>(Wl5, Wr5, w1p);
  pack_w23p_kernel<<<dim3((320 * 1024 + 255) / 256), 256, 0, stream>>>(Wmu_l, Wlv_l, Wmu_r, Wlv_r, w23p);

  // CSR build: key = dst*5 + rel
  hipMemsetAsync(cntk, 0, (size_t)NKEY * 4, stream);
  hipMemsetAsync(fillc, 0, (size_t)NKEY * 4, stream);
  hist_kernel<<<dim3((E + 255) / 256), 256, 0, stream>>>(ei, ea, cntk, E);
  const int nb = (NKEY + TS - 1) / TS;
  scan1_kernel<<<dim3(nb), 256, 0, stream>>>(cntk, offs, bsum, NKEY);
  scan2_kernel<<<dim3(1), 128, 0, stream>>>(bsum, nb);
  scan3_kernel<<<dim3((NKEY / 4 + 255) / 256 + 1), 256, 0, stream>>>(offs, bsum, NKEY, E);
  fill_kernel<<<dim3((E + 255) / 256), 256, 0, stream>>>(ei, ea, offs, fillc, perm, E);

  // layer 1: all 5 relation means (one block per node), then ONE batched GEMM dispatch
  gather1_kernel<<<dim3(N), 128, 0, stream>>>(xb, offs, perm, meanb5);
  const int mblk = (N + 127) / 128;    // 157 row-tiles of 128
  gemm_kernel<0><<<dim3(mblk * 4, 1, 5), 256, 0, stream>>>(
      meanb5, xb, w1p, hb, nullptr, nullptr,
      bl5, rmean, rvar, gamma, beta, N);

  // layer 2: one pass over hb computes z (->zb bf16) and y3 (->d_out)
  gemm_kernel<1><<<dim3(mblk * 8, 1, 1), 256, 0, stream>>>(
      hb, nullptr, w23p, nullptr, zb, (float*)d_out,
      nullptr, nullptr, nullptr, nullptr, nullptr, N);

  // fused: d_out += segment-mean(zb) + bias
  gather2_kernel<<<dim3(N), 128, 0, stream>>>(zb, offs, perm, (float*)d_out, bmu, blv, N);
}